// Round 1
// baseline (120.718 us; speedup 1.0000x reference)
//
#include <hip/hip_runtime.h>
#include <hip/hip_bf16.h>

// Problem constants (fixed by the reference setup)
#define P_ 4
#define B_ 8
#define NPIX 65536      // H*W
#define G_ 4
#define C_ 12
#define NPAIR (C_ * B_) // 96
#define KSPLIT 16       // pixel chunks per (c,b) pair
#define SLOT 24         // padded floats per pair slot: W[16], Z[4], cnt, pad

// ws layout per pair: [0..15] = W[a][g], [16..19] = Z[a], [20] = count

__global__ __launch_bounds__(256) void kld_accum_kernel(
    const float* __restrict__ act,     // [P, B, N, G]
    const int*   __restrict__ labels,  // [B, N]
    const float* __restrict__ gci,     // [P*G, C]
    float*       __restrict__ ws)      // [NPAIR][SLOT]
{
    const int pair  = blockIdx.x % NPAIR;
    const int chunk = blockIdx.x / NPAIR;
    const int c = pair / B_;
    const int b = pair % B_;

    // proj_idx[c] = argmax over rows of gci[:, c] (first max), then / G
    int best = 0;
    float bv = gci[c];
    #pragma unroll
    for (int r = 1; r < P_ * G_; ++r) {
        float v = gci[r * C_ + c];
        if (v > bv) { bv = v; best = r; }
    }
    const int proj = best / G_;

    const float* __restrict__ actp = act + (((size_t)proj * B_ + b) * (size_t)NPIX) * G_;
    const int*   __restrict__ lab  = labels + (size_t)b * NPIX;

    float acc[21];
    #pragma unroll
    for (int i = 0; i < 21; ++i) acc[i] = 0.0f;

    const int cstart = chunk * (NPIX / KSPLIT);
    const int cend   = cstart + (NPIX / KSPLIT);
    const int want   = c + 1;

    for (int n = cstart + (int)threadIdx.x; n < cend; n += 256) {
        if (lab[n] == want) {
            const float4 v = *reinterpret_cast<const float4*>(actp + (size_t)n * G_);
            float vv[4] = {v.x, v.y, v.z, v.w};
            #pragma unroll
            for (int a = 0; a < 4; ++a) {
                float e = __expf(vv[a]);
                acc[16 + a] += e;
                #pragma unroll
                for (int g = 0; g < 4; ++g) acc[a * 4 + g] += e * vv[g];
            }
            acc[20] += 1.0f;
        }
    }

    // 64-lane butterfly reduce (wavefront = 64 on CDNA)
    #pragma unroll
    for (int off = 32; off >= 1; off >>= 1) {
        #pragma unroll
        for (int i = 0; i < 21; ++i)
            acc[i] += __shfl_down(acc[i], off, 64);
    }

    if ((threadIdx.x & 63) == 0) {
        float* slot = ws + (size_t)pair * SLOT;
        #pragma unroll
        for (int i = 0; i < 21; ++i)
            atomicAdd(slot + i, acc[i]);
    }
}

__global__ __launch_bounds__(128) void kld_finalize_kernel(
    const float* __restrict__ ws,     // [NPAIR][SLOT]
    const float* __restrict__ proto,  // [C*PROTO_PER_CLASS, C] = [120, 12]
    float*       __restrict__ out)
{
    __shared__ float s_tot[128];
    __shared__ float s_den[128];
    const int t = threadIdx.x;

    float tot = 0.0f, den = 0.0f;
    if (t < NPAIR) {
        const int c = t / B_;
        // proto_ok[c] = sum over 120 rows of column c > 0
        float ps = 0.0f;
        for (int r = 0; r < 120; ++r) ps += proto[r * C_ + c];
        const float* slot = ws + (size_t)t * SLOT;
        const float cnt = slot[20];
        if (ps > 0.0f && cnt >= 2.0f) {
            float S[4][4];
            #pragma unroll
            for (int a = 0; a < 4; ++a) {
                float zinv = 1.0f / slot[16 + a];
                #pragma unroll
                for (int g = 0; g < 4; ++g)
                    S[a][g] = slot[a * 4 + g] * zinv;
            }
            #pragma unroll
            for (int j = 0; j < 4; ++j) {
                #pragma unroll
                for (int k = 0; k < 4; ++k) {
                    if (k > j) {
                        float kld = 0.5f * (S[j][j] + S[k][k] - S[j][k] - S[k][j]);
                        tot += __expf(-kld);
                    }
                }
            }
            den = 6.0f;  // G*(G-1)/2 pairs
        }
    }

    s_tot[t] = tot;
    s_den[t] = den;
    __syncthreads();
    #pragma unroll
    for (int s = 64; s >= 1; s >>= 1) {
        if (t < s) {
            s_tot[t] += s_tot[t + s];
            s_den[t] += s_den[t + s];
        }
        __syncthreads();
    }
    if (t == 0)
        out[0] = (s_den[0] > 0.0f) ? (s_tot[0] / s_den[0]) : 0.0f;
}

extern "C" void kernel_launch(void* const* d_in, const int* in_sizes, int n_in,
                              void* d_out, int out_size, void* d_ws, size_t ws_size,
                              hipStream_t stream) {
    const float* act    = (const float*)d_in[0];  // [P,B,N,G] fp32
    const int*   labels = (const int*)d_in[1];    // [B,H,W] int32
    const float* proto  = (const float*)d_in[2];  // [120, C] fp32
    const float* gci    = (const float*)d_in[3];  // [P*G, C] fp32
    float* out = (float*)d_out;
    float* ws  = (float*)d_ws;

    // zero the accumulator workspace (harness poisons d_ws with 0xAA)
    hipMemsetAsync(ws, 0, (size_t)NPAIR * SLOT * sizeof(float), stream);

    kld_accum_kernel<<<NPAIR * KSPLIT, 256, 0, stream>>>(act, labels, gci, ws);
    kld_finalize_kernel<<<1, 128, 0, stream>>>(ws, proto, out);
}